// Round 4
// baseline (151.446 us; speedup 1.0000x reference)
//
#include <hip/hip_runtime.h>
#include <hip/hip_bf16.h>

#define TT 512
#define HH 1024
#define EE 32
#define KK 4
#define II 512
#define SS 2048

using f32x4 = __attribute__((ext_vector_type(4))) float;
using s16x8 = __attribute__((ext_vector_type(8))) short;

__device__ __forceinline__ unsigned short f2bf(float f){
  unsigned int u = __builtin_bit_cast(unsigned int, f);
  u += 0x7fffu + ((u >> 16) & 1u);
  return (unsigned short)(u >> 16);
}

__device__ __forceinline__ uint4 cvt8(const float* f){
  uint4 v;
  v.x = (unsigned)f2bf(f[0]) | ((unsigned)f2bf(f[1])<<16);
  v.y = (unsigned)f2bf(f[2]) | ((unsigned)f2bf(f[3])<<16);
  v.z = (unsigned)f2bf(f[4]) | ((unsigned)f2bf(f[5])<<16);
  v.w = (unsigned)f2bf(f[6]) | ((unsigned)f2bf(f[7])<<16);
  return v;
}

// ---------------- router: logits, top-4, weights, sigmoid gate, x->bf16 -----
__global__ __launch_bounds__(64) void k_router(
    const float* __restrict__ x, const float* __restrict__ Wg,
    unsigned short* __restrict__ xb, int* __restrict__ topk_idx,
    float* __restrict__ topk_w, float* __restrict__ sig_gate){
  int t = blockIdx.x; int l = threadIdx.x;
  const float* xr = x + (size_t)t * HH;
  #pragma unroll
  for(int i=0;i<HH/64;i++){
    int h = l + 64*i;
    xb[(size_t)t*HH + h] = f2bf(xr[h]);
  }
  float acc0=0.f, acc1=0.f, acc2=0.f, acc3=0.f;
  if(l < EE+1){
    const float* wcol = Wg + l;
    for(int h=0; h<HH; h+=4){
      acc0 += xr[h]   * wcol[(size_t)h*(EE+1)];
      acc1 += xr[h+1] * wcol[(size_t)(h+1)*(EE+1)];
      acc2 += xr[h+2] * wcol[(size_t)(h+2)*(EE+1)];
      acc3 += xr[h+3] * wcol[(size_t)(h+3)*(EE+1)];
    }
  }
  __shared__ float lg[EE+1];
  if(l < EE+1) lg[l] = (acc0+acc1)+(acc2+acc3);
  __syncthreads();
  if(l == 0){
    float v[EE];
    #pragma unroll
    for(int i=0;i<EE;i++) v[i]=lg[i];
    int idx[KK]; float val[KK];
    #pragma unroll
    for(int k=0;k<KK;k++){
      float m=-1e30f; int mi=0;
      for(int i=0;i<EE;i++){ if(v[i]>m){ m=v[i]; mi=i; } }
      idx[k]=mi; val[k]=m; v[mi]=-1e30f;
    }
    float mx = val[0], s=0.f; float w[KK];
    #pragma unroll
    for(int k=0;k<KK;k++){ w[k]=__expf(val[k]-mx); s+=w[k]; }
    float inv = 1.f/s;
    #pragma unroll
    for(int k=0;k<KK;k++){ topk_idx[t*KK+k]=idx[k]; topk_w[t*KK+k]=w[k]*inv; }
    sig_gate[t] = 1.f/(1.f+__expf(-lg[EE]));
  }
}

// ---------------- per-expert token list (deterministic compaction) ----------
__global__ __launch_bounds__(64) void k_build(
    const int* __restrict__ topk_idx, const float* __restrict__ topk_w,
    int* __restrict__ token_list, float* __restrict__ weight_list,
    int* __restrict__ counts){
  int e = blockIdx.x; int l = threadIdx.x;
  int cnt = 0;
  for(int c=0;c<TT;c+=64){
    int t = c + l;
    int kk = -1;
    #pragma unroll
    for(int k=0;k<KK;k++) if(topk_idx[t*KK+k]==e) kk=k;
    unsigned long long b = __ballot(kk>=0);
    int pre = __popcll(b & ((1ull<<l)-1ull));
    if(kk>=0){
      token_list[e*TT + cnt + pre] = t;
      weight_list[e*TT + cnt + pre] = topk_w[t*KK+kk];
    }
    cnt += __popcll(b);
  }
  if(l==0) counts[e]=cnt;
}

// ============ core GEMM: C(M x 64) += A(M x K) * B(K x 64), K-step 32 =======
// RG = M/64 row-groups (1 or 2). DUAL: two B matrices sharing the A tile.
// LDS pitch 40 ushorts (80 B): uint4 writes/b128 reads hit the 32-bank floor.
// A thread role: ar=tid>>2 (row), as_=tid&3 (16B seg); advances 32 elems/step.
// B thread role: n=tid&63 (col), kh=tid>>6 (8-row group); 8 strided dwords.
template<int RG, bool DUAL>
__device__ __forceinline__ void gemm64(
    const unsigned short* A0, const unsigned short* A1, bool va,
    const float* Gp, const float* Up, int ldb, int NK,
    f32x4 (*ag)[4], f32x4 (*au)[4],
    unsigned short* As, unsigned short* Bg, unsigned short* Bu, int tid){
  const int MR = RG*64;
  const int w = tid>>6, l = tid&63;
  const int n = tid&63, kh = tid>>6, ar = tid>>2, as_ = tid&3;
  const int kt = l>>4, mm = l&15;
  uint4 av0 = make_uint4(0,0,0,0), av1 = make_uint4(0,0,0,0);
  float gv[8], uv[8];
  if(va) av0 = *reinterpret_cast<const uint4*>(A0);
  if(RG==2) av1 = *reinterpret_cast<const uint4*>(A1);
  #pragma unroll
  for(int i=0;i<8;i++) gv[i] = Gp[(size_t)i*ldb];
  if(DUAL){
    #pragma unroll
    for(int i=0;i<8;i++) uv[i] = Up[(size_t)i*ldb];
  }
  *reinterpret_cast<uint4*>(As + (size_t)ar*40 + as_*8) = av0;
  if(RG==2) *reinterpret_cast<uint4*>(As + (size_t)(64+ar)*40 + as_*8) = av1;
  *reinterpret_cast<uint4*>(Bg + (size_t)n*40 + kh*8) = cvt8(gv);
  if(DUAL) *reinterpret_cast<uint4*>(Bu + (size_t)n*40 + kh*8) = cvt8(uv);
  __syncthreads();
  for(int ks=0; ks<NK; ks++){
    const int cur = ks & 1;
    const bool more = (ks+1 < NK);
    if(more){
      av0 = make_uint4(0,0,0,0);
      if(va) av0 = *reinterpret_cast<const uint4*>(A0 + (size_t)(ks+1)*32);
      if(RG==2) av1 = *reinterpret_cast<const uint4*>(A1 + (size_t)(ks+1)*32);
      const float* g = Gp + (size_t)(ks+1)*32*ldb;
      #pragma unroll
      for(int i=0;i<8;i++) gv[i] = g[(size_t)i*ldb];
      if(DUAL){
        const float* u = Up + (size_t)(ks+1)*32*ldb;
        #pragma unroll
        for(int i=0;i<8;i++) uv[i] = u[(size_t)i*ldb];
      }
    }
    s16x8 bg_[4], bu_[4];
    #pragma unroll
    for(int c=0;c<4;c++){
      bg_[c] = *reinterpret_cast<const s16x8*>(Bg + ((size_t)cur*64 + c*16 + mm)*40 + kt*8);
      if(DUAL)
        bu_[c] = *reinterpret_cast<const s16x8*>(Bu + ((size_t)cur*64 + c*16 + mm)*40 + kt*8);
    }
    #pragma unroll
    for(int rg=0; rg<RG; rg++){
      s16x8 af = *reinterpret_cast<const s16x8*>(As + ((size_t)cur*MR + rg*64 + w*16 + mm)*40 + kt*8);
      #pragma unroll
      for(int c=0;c<4;c++){
        ag[rg][c] = __builtin_amdgcn_mfma_f32_16x16x32_bf16(af, bg_[c], ag[rg][c], 0,0,0);
        if(DUAL)
          au[rg][c] = __builtin_amdgcn_mfma_f32_16x16x32_bf16(af, bu_[c], au[rg][c], 0,0,0);
      }
    }
    if(more){
      const int nx = cur^1;
      *reinterpret_cast<uint4*>(As + ((size_t)nx*MR + ar)*40 + as_*8) = av0;
      if(RG==2) *reinterpret_cast<uint4*>(As + ((size_t)nx*MR + 64 + ar)*40 + as_*8) = av1;
      *reinterpret_cast<uint4*>(Bg + ((size_t)nx*64 + n)*40 + kh*8) = cvt8(gv);
      if(DUAL) *reinterpret_cast<uint4*>(Bu + ((size_t)nx*64 + n)*40 + kh*8) = cvt8(uv);
    }
    __syncthreads();
  }
}

// ---------------- phase 2: ALL gate-up (shared M=128/N=64, expert M=64/N=64) -
__global__ __launch_bounds__(256) void k_gateup_all(
    const unsigned short* __restrict__ xb,
    const float* __restrict__ Wsg, const float* __restrict__ Wsu,
    unsigned short* __restrict__ Hs,
    const float* __restrict__ Wgate, const float* __restrict__ Wup,
    const int* __restrict__ token_list, const int* __restrict__ counts,
    unsigned short* __restrict__ hbuf){
  __shared__ unsigned short As[2*128*40];   // 20.5 KB
  __shared__ unsigned short Bg[2*64*40];    // 10.25 KB
  __shared__ unsigned short Bu[2*64*40];    // 10.25 KB
  int tid = threadIdx.x, w = tid>>6, l = tid&63;
  int ar = tid>>2, as_ = tid&3, n = tid&63, kh = tid>>6;
  int bid = blockIdx.x;
  f32x4 zero = {0.f,0.f,0.f,0.f};
  const int NSH = (TT/128)*(SS/64);   // 4*32 = 128

  if(bid < NSH){
    int n0 = (bid & 31) * 64;
    int r0 = (bid >> 5) * 128;
    f32x4 ag[2][4], au[2][4];
    #pragma unroll
    for(int rg=0;rg<2;rg++)
      #pragma unroll
      for(int c=0;c<4;c++){ ag[rg][c]=zero; au[rg][c]=zero; }
    const unsigned short* A0 = xb + (size_t)(r0+ar)*HH + as_*8;
    const unsigned short* A1 = A0 + (size_t)64*HH;
    const float* Gp = Wsg + (size_t)(kh*8)*SS + n0 + n;
    const float* Up = Wsu + (size_t)(kh*8)*SS + n0 + n;
    gemm64<2,true>(A0, A1, true, Gp, Up, SS, HH/32, ag, au, As, Bg, Bu, tid);
    int mm = l&15;
    #pragma unroll
    for(int rg=0;rg<2;rg++){
      int rb = r0 + rg*64 + w*16 + (l>>4)*4;
      #pragma unroll
      for(int c=0;c<4;c++){
        #pragma unroll
        for(int j=0;j<4;j++){
          float g = ag[rg][c][j], u = au[rg][c][j];
          Hs[(size_t)(rb+j)*SS + n0 + c*16 + mm] = f2bf(g*u/(1.f+__expf(-g)));
        }
      }
    }
  } else {
    int b = bid - NSH;
    int e = b >> 3;            // II/64 = 8 tiles per expert
    int i0 = (b & 7) * 64;
    int cnt = counts[e]; if(cnt == 0) return;
    int off = 0;
    for(int i=0;i<e;i++) off += counts[i];
    const float* Bg0 = Wgate + (size_t)e*HH*II;
    const float* Bu0 = Wup   + (size_t)e*HH*II;
    for(int rt=0; rt*64<cnt; rt++){
      int nv = cnt - rt*64; if(nv > 64) nv = 64;
      const int* rows = token_list + e*TT + rt*64;
      int arow = (ar < nv) ? rows[ar] : 0;
      bool va = ar < nv;
      f32x4 ag[1][4], au[1][4];
      #pragma unroll
      for(int c=0;c<4;c++){ ag[0][c]=zero; au[0][c]=zero; }
      const unsigned short* A0 = xb + (size_t)arow*HH + as_*8;
      const float* Gp = Bg0 + (size_t)(kh*8)*II + i0 + n;
      const float* Up = Bu0 + (size_t)(kh*8)*II + i0 + n;
      gemm64<1,true>(A0, A0, va, Gp, Up, II, HH/32, ag, au, As, Bg, Bu, tid);
      int mm = l&15, rr0 = w*16 + (l>>4)*4;
      #pragma unroll
      for(int c=0;c<4;c++){
        #pragma unroll
        for(int j=0;j<4;j++){
          int rr = rr0 + j;
          if(rr < nv){
            float g = ag[0][c][j], u = au[0][c][j];
            hbuf[(size_t)(off+rt*64+rr)*II + i0 + c*16 + mm] =
                f2bf(g*u/(1.f+__expf(-g)));
          }
        }
      }
    }
  }
}

// ---------------- phase 3: ALL down (shared M=128/N=64, expert M=64/N=64) ---
__global__ __launch_bounds__(256) void k_down_all(
    const unsigned short* __restrict__ Hsrc, const float* __restrict__ Wsd,
    const float* __restrict__ sig_gate,
    const unsigned short* __restrict__ hbuf, const float* __restrict__ Wdown,
    const int* __restrict__ token_list, const float* __restrict__ weight_list,
    const int* __restrict__ counts, float* __restrict__ out){
  __shared__ unsigned short As[2*128*40];   // 20.5 KB
  __shared__ unsigned short Bs[2*64*40];    // 10.25 KB
  int tid = threadIdx.x, w = tid>>6, l = tid&63;
  int ar = tid>>2, as_ = tid&3, n = tid&63, kh = tid>>6;
  int bid = blockIdx.x;
  f32x4 zero = {0.f,0.f,0.f,0.f};
  const int NSH = (TT/128)*(HH/64);   // 4*16 = 64

  if(bid < NSH){
    int n0 = (bid & 15) * 64;
    int r0 = (bid >> 4) * 128;
    f32x4 acc[2][4];
    #pragma unroll
    for(int rg=0;rg<2;rg++)
      #pragma unroll
      for(int c=0;c<4;c++) acc[rg][c]=zero;
    const unsigned short* A0 = Hsrc + (size_t)(r0+ar)*SS + as_*8;
    const unsigned short* A1 = A0 + (size_t)64*SS;
    const float* Bp = Wsd + (size_t)(kh*8)*HH + n0 + n;
    gemm64<2,false>(A0, A1, true, Bp, Bp, HH, SS/32, acc, acc, As, Bs, Bs, tid);
    int mm = l&15;
    #pragma unroll
    for(int rg=0;rg<2;rg++){
      int rb = r0 + rg*64 + w*16 + (l>>4)*4;
      #pragma unroll
      for(int c=0;c<4;c++){
        #pragma unroll
        for(int j=0;j<4;j++){
          atomicAdd(&out[(size_t)(rb+j)*HH + n0 + c*16 + mm],
                    sig_gate[rb+j]*acc[rg][c][j]);
        }
      }
    }
  } else {
    int b = bid - NSH;
    int e = b >> 4;            // HH/64 = 16 tiles per expert
    int n0 = (b & 15) * 64;
    int cnt = counts[e]; if(cnt == 0) return;
    int off = 0;
    for(int i=0;i<e;i++) off += counts[i];
    const float* B0 = Wdown + (size_t)e*II*HH;
    for(int rt=0; rt*64<cnt; rt++){
      int nv = cnt - rt*64; if(nv > 64) nv = 64;
      bool va = ar < nv;
      f32x4 acc[1][4];
      #pragma unroll
      for(int c=0;c<4;c++) acc[0][c]=zero;
      const unsigned short* A0 = hbuf + (size_t)(off+rt*64+ar)*II + as_*8;
      const float* Bp = B0 + (size_t)(kh*8)*HH + n0 + n;
      gemm64<1,false>(A0, A0, va, Bp, Bp, HH, II/32, acc, acc, As, Bs, Bs, tid);
      int mm = l&15, rr0 = w*16 + (l>>4)*4;
      #pragma unroll
      for(int c=0;c<4;c++){
        #pragma unroll
        for(int j=0;j<4;j++){
          int rr = rr0 + j;
          if(rr < nv){
            int t = token_list[e*TT + rt*64 + rr];
            float wt = weight_list[e*TT + rt*64 + rr];
            atomicAdd(&out[(size_t)t*HH + n0 + c*16 + mm], wt*acc[0][c][j]);
          }
        }
      }
    }
  }
}

extern "C" void kernel_launch(void* const* d_in, const int* in_sizes, int n_in,
                              void* d_out, int out_size, void* d_ws, size_t ws_size,
                              hipStream_t stream) {
  const float* x     = (const float*)d_in[0];
  const float* Wg    = (const float*)d_in[1];
  const float* Wgate = (const float*)d_in[2];
  const float* Wup   = (const float*)d_in[3];
  const float* Wdown = (const float*)d_in[4];
  const float* Wsg   = (const float*)d_in[5];
  const float* Wsu   = (const float*)d_in[6];
  const float* Wsd   = (const float*)d_in[7];
  float* out = (float*)d_out;

  char* ws = (char*)d_ws;
  unsigned short* xb   = (unsigned short*)ws; ws += (size_t)TT*HH*2;
  unsigned short* Hs   = (unsigned short*)ws; ws += (size_t)TT*SS*2;
  unsigned short* hbuf = (unsigned short*)ws; ws += (size_t)(TT*KK+64)*II*2;
  int*   token_list  = (int*)ws;   ws += (size_t)EE*TT*4;
  float* weight_list = (float*)ws; ws += (size_t)EE*TT*4;
  int*   topk_idx    = (int*)ws;   ws += (size_t)TT*KK*4;
  float* topk_wq     = (float*)ws; ws += (size_t)TT*KK*4;
  int*   counts      = (int*)ws;   ws += 128;
  float* sig_gate    = (float*)ws; ws += (size_t)TT*4;

  hipMemsetAsync(d_out, 0, (size_t)TT*HH*4, stream);
  k_router<<<TT, 64, 0, stream>>>(x, Wg, xb, topk_idx, topk_wq, sig_gate);
  k_build<<<EE, 64, 0, stream>>>(topk_idx, topk_wq, token_list, weight_list, counts);
  k_gateup_all<<<(TT/128)*(SS/64) + EE*(II/64), 256, 0, stream>>>(
      xb, Wsg, Wsu, Hs, Wgate, Wup, token_list, counts, hbuf);
  k_down_all<<<(TT/128)*(HH/64) + EE*(HH/64), 256, 0, stream>>>(
      Hs, Wsd, sig_gate, hbuf, Wdown, token_list, weight_list, counts, out);
}